// Round 9
// baseline (408.757 us; speedup 1.0000x reference)
//
#include <hip/hip_runtime.h>

typedef unsigned int uint;
typedef unsigned short ushort;

#define IN_C 128
#define HID  32

// ---- bf16 helpers (fp32 accumulate everywhere; RNE on store) --------------
__device__ __forceinline__ float bf_lo(uint u) { return __uint_as_float(u << 16); }
__device__ __forceinline__ float bf_hi(uint u) { return __uint_as_float(u & 0xffff0000u); }
__device__ __forceinline__ uint  f2bf(float f) {
    uint u = __float_as_uint(f);
    return (u + 0x7fffu + ((u >> 16) & 1u)) >> 16;   // RNE; inputs are finite
}
__device__ __forceinline__ float inv_sqrt_deg(int d) {
    return d > 0 ? 1.f / sqrtf((float)d) : 0.f;      // matches reference norm()
}
__device__ __forceinline__ int lower_bound(const int* __restrict__ a, int sz, int key) {
    int lo = 0, hi = sz;
    while (lo < hi) { int m = (lo + hi) >> 1; if (a[m] < key) lo = m + 1; else hi = m; }
    return lo;
}

// ---------------------------------------------------------------------------
// K1: fused prep (single dispatch, independent block groups — keeps the graph
// front-end busy; R8's split+serialize regressed 173 µs under harness DMA):
//   blocks [0,nbE)        : r0 = relu(x @ w_embed) -> bf16, plus pre-scaled
//                           y1_0 = dis1.*r0, y2_0 = dis2.*r0 (degrees via own
//                           binary searches — no dependency on ip arrays)
//   blocks [nbE,nbE+nbI)  : both CSR indptrs by binary search
//   blocks [nbE+nbI,+nbT) : warm-touch A2 col list into LLC
// ---------------------------------------------------------------------------
__global__ void prep_kernel(const float* __restrict__ x,
                            const float* __restrict__ w,
                            ushort* __restrict__ r0,
                            ushort* __restrict__ y1, ushort* __restrict__ y2,
                            const int* __restrict__ a1r, int E1, int* __restrict__ ip1,
                            const int* __restrict__ a2r, int E2, int* __restrict__ ip2,
                            const int* __restrict__ a2c, int* __restrict__ dummy,
                            int n, int nbE, int nbI, int nbT) {
    __shared__ float wl[IN_C * HID];
    const int tid = threadIdx.x;
    if (blockIdx.x < nbE) {
        for (int i = tid; i < IN_C * HID; i += blockDim.x) wl[i] = w[i];
        __syncthreads();
        const int row = blockIdx.x * 16 + tid / 16;
        const int h0  = (tid % 16) * 2;
        if (row >= n) return;
        const float4* xr = (const float4*)(x + (size_t)row * IN_C);
        float a0 = 0.f, a1 = 0.f;
#pragma unroll
        for (int k4 = 0; k4 < IN_C / 4; ++k4) {
            float4 xv = xr[k4];
            a0 += xv.x * wl[(4*k4+0)*HID + h0];  a1 += xv.x * wl[(4*k4+0)*HID + h0+1];
            a0 += xv.y * wl[(4*k4+1)*HID + h0];  a1 += xv.y * wl[(4*k4+1)*HID + h0+1];
            a0 += xv.z * wl[(4*k4+2)*HID + h0];  a1 += xv.z * wl[(4*k4+2)*HID + h0+1];
            a0 += xv.w * wl[(4*k4+3)*HID + h0];  a1 += xv.w * wl[(4*k4+3)*HID + h0+1];
        }
        a0 = fmaxf(a0, 0.f); a1 = fmaxf(a1, 0.f);
        // own-degree binary searches (same addresses across the 16-thread
        // group -> broadcast loads; top tree levels are cache-hot)
        const int d1 = lower_bound(a1r, E1, row + 1) - lower_bound(a1r, E1, row);
        const int d2 = lower_bound(a2r, E2, row + 1) - lower_bound(a2r, E2, row);
        const float s1 = inv_sqrt_deg(d1);
        const float s2 = inv_sqrt_deg(d2);
        const size_t o = (size_t)row * 16 + (tid % 16);
        ((uint*)r0)[o] = f2bf(a0)      | (f2bf(a1)      << 16);
        ((uint*)y1)[o] = f2bf(s1 * a0) | (f2bf(s1 * a1) << 16);
        ((uint*)y2)[o] = f2bf(s2 * a0) | (f2bf(s2 * a1) << 16);
    } else if (blockIdx.x < nbE + nbI) {
        const int i = (blockIdx.x - nbE) * 256 + tid;
        if (i > n) return;
        ip1[i] = lower_bound(a1r, E1, i);
        ip2[i] = lower_bound(a2r, E2, i);
    } else {
        const int t = (blockIdx.x - nbE - nbI) * 256 + tid;
        const int stride = nbT * 256;
        const int total4 = E2 / 4;
        const int4* c4 = (const int4*)a2c;
        int s = 0;
        for (int i = t; i < total4; i += stride) { int4 u = c4[i]; s += u.x + u.y + u.z + u.w; }
        if (s == -123456789) dummy[0] = s;   // defeats DCE; never taken in practice
    }
}

// ---------------------------------------------------------------------------
// K2/K3: fused-level SpMM + ReLU, pre-scaled bf16 features / fp32 accumulate.
// No val loads: inner loop is col + gather-of-y, plain adds; row-side dis
// applied once in the epilogue (relu(d*S) == d*relu(S), d>=0).
// ROWS rows per wave; L = C/8 feature-lanes (uint4 = 8 bf16) x W edge-ways,
// 4-edge int4 batches (VGPR ~32; TLP > per-wave ILP here — R5/R6 evidence).
// Blocks [0,nb2) = A2 (heavy, out col off C, gathers yin2); rest = A1.
// If SCALED: also emit yout1/yout2 = dis1/dis2-scaled output (next level).
// ---------------------------------------------------------------------------
template <int C, int ROWS, bool SCALED>
__global__ __launch_bounds__(256) void spmm_level(
        const int* __restrict__ ip1, const int* __restrict__ col1,
        const int* __restrict__ ip2, const int* __restrict__ col2,
        const ushort* __restrict__ yin1, const ushort* __restrict__ yin2,
        ushort* __restrict__ rout,
        ushort* __restrict__ yout1, ushort* __restrict__ yout2,
        int n, int nb2) {
    constexpr int L    = C / 8;        // feature lanes per row
    constexpr int SUBL = 64 / ROWS;    // lanes per row
    constexpr int W    = SUBL / L;     // edge ways per row
    const int lane = threadIdx.x & 63;
    const int wave = threadIdx.x >> 6;
    const int sub  = lane / SUBL;
    const int li   = lane % SUBL;
    const int fl   = li % L;
    const int way  = li / L;

    int bid = blockIdx.x;
    const int* ip; const int* col; const ushort* yin; int off;
    if (bid < nb2) {             ip = ip2; col = col2; yin = yin2; off = C; }
    else           { bid -= nb2; ip = ip1; col = col1; yin = yin1; off = 0; }

    const int row = (bid * 4 + wave) * ROWS + sub;
    if (row >= n) return;

    const ushort* xbase = yin + fl * 8;
    float acc[8];
#pragma unroll
    for (int j = 0; j < 8; ++j) acc[j] = 0.f;

    auto gat = [&](int c) -> uint4 {
        return *(const uint4*)(xbase + (size_t)c * C);
    };
    auto aadd = [&](const uint4& u) {
        acc[0] += bf_lo(u.x); acc[1] += bf_hi(u.x);
        acc[2] += bf_lo(u.y); acc[3] += bf_hi(u.y);
        acc[4] += bf_lo(u.z); acc[5] += bf_hi(u.z);
        acc[6] += bf_lo(u.w); acc[7] += bf_hi(u.w);
    };

    const int s = ip[row];
    const int e = ip[row + 1];
    int sv = (s + 3) & ~3; if (sv > e) sv = e;     // 16B-align vector loads
    const int nv = (e - sv) / (4 * W);

    // unaligned head (<=3 edges)
    for (int idx = s + way; idx < sv; idx += W) aadd(gat(col[idx]));

    // vector body: 4 edges per way per iteration (int4 col + 4 gathers)
    const int* cb = col + sv;
    for (int i = 0; i < nv; ++i) {
        const int base = (i * W + way) * 4;
        const int4 cc = *(const int4*)(cb + base);
        const uint4 g0 = gat(cc.x), g1 = gat(cc.y), g2 = gat(cc.z), g3 = gat(cc.w);
        aadd(g0); aadd(g1); aadd(g2); aadd(g3);
    }
    // scalar tail
    for (int idx = sv + nv * 4 * W + way; idx < e; idx += W) aadd(gat(col[idx]));

    // cross-way in-register reduction (stays within each row's subgroup)
#pragma unroll
    for (int m = L; m < SUBL; m <<= 1)
#pragma unroll
        for (int j = 0; j < 8; ++j) acc[j] += __shfl_xor(acc[j], m, 64);

    if (way == 0) {
        const float dsown = inv_sqrt_deg(e - s);    // row-side normalization
        float r[8];
#pragma unroll
        for (int j = 0; j < 8; ++j) r[j] = fmaxf(dsown * acc[j], 0.f);

        const size_t oidx = (size_t)row * (2 * C) + off + fl * 8;
        uint4 p;
        p.x = f2bf(r[0]) | (f2bf(r[1]) << 16);
        p.y = f2bf(r[2]) | (f2bf(r[3]) << 16);
        p.z = f2bf(r[4]) | (f2bf(r[5]) << 16);
        p.w = f2bf(r[6]) | (f2bf(r[7]) << 16);
        *(uint4*)(rout + oidx) = p;

        if (SCALED) {
            const float s1 = inv_sqrt_deg(ip1[row + 1] - ip1[row]);
            const float s2 = inv_sqrt_deg(ip2[row + 1] - ip2[row]);
            uint4 q1, q2;
            q1.x = f2bf(s1*r[0]) | (f2bf(s1*r[1]) << 16);
            q1.y = f2bf(s1*r[2]) | (f2bf(s1*r[3]) << 16);
            q1.z = f2bf(s1*r[4]) | (f2bf(s1*r[5]) << 16);
            q1.w = f2bf(s1*r[6]) | (f2bf(s1*r[7]) << 16);
            q2.x = f2bf(s2*r[0]) | (f2bf(s2*r[1]) << 16);
            q2.y = f2bf(s2*r[2]) | (f2bf(s2*r[3]) << 16);
            q2.z = f2bf(s2*r[4]) | (f2bf(s2*r[5]) << 16);
            q2.w = f2bf(s2*r[6]) | (f2bf(s2*r[7]) << 16);
            *(uint4*)(yout1 + oidx) = q1;
            *(uint4*)(yout2 + oidx) = q2;
        }
    }
}

// ---------------------------------------------------------------------------
// K4: out = [r0 | r1 | r2] @ w_classify  (bf16 features, fp32 weights in LDS)
// ---------------------------------------------------------------------------
#define CDIM 224
#define OUT_C 16
__global__ void classify_kernel(const ushort* __restrict__ r0,
                                const ushort* __restrict__ r1,
                                const ushort* __restrict__ r2,
                                const float* __restrict__ w,
                                float* __restrict__ out, int n) {
    __shared__ float wl[CDIM * OUT_C];
    const int tid = threadIdx.x;
    for (int i = tid; i < CDIM * OUT_C; i += blockDim.x) wl[i] = w[i];
    __syncthreads();
    const int row = blockIdx.x * 16 + tid / 16;
    const int o   = tid % 16;
    if (row >= n) return;
    float acc = 0.f;

    const uint4* a = (const uint4*)(r0 + (size_t)row * 32);
#pragma unroll
    for (int q = 0; q < 4; ++q) {
        uint4 u = a[q]; int j = q * 8;
        acc += bf_lo(u.x) * wl[(j+0)*OUT_C + o];  acc += bf_hi(u.x) * wl[(j+1)*OUT_C + o];
        acc += bf_lo(u.y) * wl[(j+2)*OUT_C + o];  acc += bf_hi(u.y) * wl[(j+3)*OUT_C + o];
        acc += bf_lo(u.z) * wl[(j+4)*OUT_C + o];  acc += bf_hi(u.z) * wl[(j+5)*OUT_C + o];
        acc += bf_lo(u.w) * wl[(j+6)*OUT_C + o];  acc += bf_hi(u.w) * wl[(j+7)*OUT_C + o];
    }
    const uint4* b = (const uint4*)(r1 + (size_t)row * 64);
#pragma unroll
    for (int q = 0; q < 8; ++q) {
        uint4 u = b[q]; int j = 32 + q * 8;
        acc += bf_lo(u.x) * wl[(j+0)*OUT_C + o];  acc += bf_hi(u.x) * wl[(j+1)*OUT_C + o];
        acc += bf_lo(u.y) * wl[(j+2)*OUT_C + o];  acc += bf_hi(u.y) * wl[(j+3)*OUT_C + o];
        acc += bf_lo(u.z) * wl[(j+4)*OUT_C + o];  acc += bf_hi(u.z) * wl[(j+5)*OUT_C + o];
        acc += bf_lo(u.w) * wl[(j+6)*OUT_C + o];  acc += bf_hi(u.w) * wl[(j+7)*OUT_C + o];
    }
    const uint4* c = (const uint4*)(r2 + (size_t)row * 128);
#pragma unroll
    for (int q = 0; q < 16; ++q) {
        uint4 u = c[q]; int j = 96 + q * 8;
        acc += bf_lo(u.x) * wl[(j+0)*OUT_C + o];  acc += bf_hi(u.x) * wl[(j+1)*OUT_C + o];
        acc += bf_lo(u.y) * wl[(j+2)*OUT_C + o];  acc += bf_hi(u.y) * wl[(j+3)*OUT_C + o];
        acc += bf_lo(u.z) * wl[(j+4)*OUT_C + o];  acc += bf_hi(u.z) * wl[(j+5)*OUT_C + o];
        acc += bf_lo(u.w) * wl[(j+6)*OUT_C + o];  acc += bf_hi(u.w) * wl[(j+7)*OUT_C + o];
    }
    out[(size_t)row * OUT_C + o] = acc;
}

// ---------------------------------------------------------------------------
extern "C" void kernel_launch(void* const* d_in, const int* in_sizes, int n_in,
                              void* d_out, int out_size, void* d_ws, size_t ws_size,
                              hipStream_t stream) {
    const float* x   = (const float*)d_in[0];
    const float* we  = (const float*)d_in[1];
    const float* wc  = (const float*)d_in[2];
    const int*   a1r = (const int*)  d_in[3];
    const int*   a1c = (const int*)  d_in[4];
    const int*   a2r = (const int*)  d_in[6];
    const int*   a2c = (const int*)  d_in[7];
    float* out = (float*)d_out;

    const int E1 = in_sizes[3];
    const int E2 = in_sizes[6];
    const int n  = in_sizes[0] / IN_C;   // 20000

    // Workspace (bf16): r0[n*32] r1[n*64] r2[n*128] y1_0[n*32] y2_0[n*32]
    //                   y1_1[n*64] y2_1[n*64], then ip1/ip2/dummy (int)
    ushort* r0   = (ushort*)d_ws;
    ushort* r1   = r0   + (size_t)n * 32;
    ushort* r2   = r1   + (size_t)n * 64;
    ushort* y1_0 = r2   + (size_t)n * 128;
    ushort* y2_0 = y1_0 + (size_t)n * 32;
    ushort* y1_1 = y2_0 + (size_t)n * 32;
    ushort* y2_1 = y1_1 + (size_t)n * 64;
    int*    ip1  = (int*)(y2_1 + (size_t)n * 64);
    int*    ip2  = ip1 + (n + 1);
    int*    dummy = ip2 + (n + 1);

    // K1: fused prep (embed+scale, indptrs, warm-touch) — one dispatch
    {
        const int nbE = (n + 15) / 16;
        const int nbI = (n + 1 + 255) / 256;
        const int nbT = 512;
        prep_kernel<<<nbE + nbI + nbT, 256, 0, stream>>>(
            x, we, r0, y1_0, y2_0, a1r, E1, ip1, a2r, E2, ip2, a2c, dummy,
            n, nbE, nbI, nbT);
    }
    // K2: level 1 (C=32, ROWS=2 -> W=8); writes r1 + y1_1 + y2_1
    {
        const int nb = (n + 7) / 8;
        spmm_level<32, 2, true><<<2 * nb, 256, 0, stream>>>(
            ip1, a1c, ip2, a2c, y1_0, y2_0, r1, y1_1, y2_1, n, nb);
    }
    // K3: level 2 (C=64, ROWS=1 -> W=8); writes r2 only
    {
        const int nb = (n + 3) / 4;
        spmm_level<64, 1, false><<<2 * nb, 256, 0, stream>>>(
            ip1, a1c, ip2, a2c, y1_1, y2_1, r2, nullptr, nullptr, n, nb);
    }
    // K4: fused concat + classify
    classify_kernel<<<(n + 15) / 16, 256, 0, stream>>>(r0, r1, r2, wc, out, n);
}

// Round 10
// 220.992 us; speedup vs baseline: 1.8496x; 1.8496x over previous
//
#include <hip/hip_runtime.h>

typedef unsigned int uint;
typedef unsigned short ushort;

#define IN_C 128
#define HID  32

// ---- bf16 helpers (fp32 accumulate everywhere; RNE on store) --------------
__device__ __forceinline__ float bf_lo(uint u) { return __uint_as_float(u << 16); }
__device__ __forceinline__ float bf_hi(uint u) { return __uint_as_float(u & 0xffff0000u); }
__device__ __forceinline__ uint  f2bf(float f) {
    uint u = __float_as_uint(f);
    return (u + 0x7fffu + ((u >> 16) & 1u)) >> 16;   // RNE; inputs are finite
}
__device__ __forceinline__ float inv_sqrt_deg(int d) {
    return d > 0 ? 1.f / sqrtf((float)d) : 0.f;      // matches reference norm()
}

// ---------------------------------------------------------------------------
// K1: fused prep — EXACT R7 structure (fast under the harness DMA flood):
//   blocks [0,nbE)        : r0 = relu(x @ w_embed) -> bf16 (no degree use!)
//   blocks [nbE,nbE+nbI)  : both CSR indptrs by binary search
//   blocks [nbE+nbI,+nbT) : warm-touch A2 col+val into LLC
// ---------------------------------------------------------------------------
__global__ void prep_kernel(const float* __restrict__ x,
                            const float* __restrict__ w,
                            ushort* __restrict__ r0,
                            const int* __restrict__ a1r, int E1, int* __restrict__ ip1,
                            const int* __restrict__ a2r, int E2, int* __restrict__ ip2,
                            const int* __restrict__ a2c, const float* __restrict__ a2v,
                            float* __restrict__ dummy,
                            int n, int nbE, int nbI, int nbT) {
    __shared__ float wl[IN_C * HID];
    const int tid = threadIdx.x;
    if (blockIdx.x < nbE) {
        for (int i = tid; i < IN_C * HID; i += blockDim.x) wl[i] = w[i];
        __syncthreads();
        const int row = blockIdx.x * 16 + tid / 16;
        const int h0  = (tid % 16) * 2;
        if (row >= n) return;
        const float4* xr = (const float4*)(x + (size_t)row * IN_C);
        float a0 = 0.f, a1 = 0.f;
#pragma unroll
        for (int k4 = 0; k4 < IN_C / 4; ++k4) {
            float4 xv = xr[k4];
            a0 += xv.x * wl[(4*k4+0)*HID + h0];  a1 += xv.x * wl[(4*k4+0)*HID + h0+1];
            a0 += xv.y * wl[(4*k4+1)*HID + h0];  a1 += xv.y * wl[(4*k4+1)*HID + h0+1];
            a0 += xv.z * wl[(4*k4+2)*HID + h0];  a1 += xv.z * wl[(4*k4+2)*HID + h0+1];
            a0 += xv.w * wl[(4*k4+3)*HID + h0];  a1 += xv.w * wl[(4*k4+3)*HID + h0+1];
        }
        uint p = f2bf(fmaxf(a0, 0.f)) | (f2bf(fmaxf(a1, 0.f)) << 16);
        ((uint*)r0)[(size_t)row * 16 + (tid % 16)] = p;
    } else if (blockIdx.x < nbE + nbI) {
        const int i = (blockIdx.x - nbE) * 256 + tid;
        if (i > n) return;
        int lo = 0, hi = E1;
        while (lo < hi) { int m = (lo + hi) >> 1; if (a1r[m] < i) lo = m + 1; else hi = m; }
        ip1[i] = lo;
        lo = 0; hi = E2;
        while (lo < hi) { int m = (lo + hi) >> 1; if (a2r[m] < i) lo = m + 1; else hi = m; }
        ip2[i] = lo;
    } else {
        const int t = (blockIdx.x - nbE - nbI) * 256 + tid;
        const int stride = nbT * 256;
        const int total4 = E2 / 4;
        const float4* c4 = (const float4*)a2c;
        const float4* v4 = (const float4*)a2v;
        float s = 0.f;
        for (int i = t; i < total4; i += stride) {
            float4 u = c4[i], v = v4[i];
            s += u.x + u.y + u.z + u.w + v.x + v.y + v.z + v.w;
        }
        if (s == 123.456f) dummy[0] = s;   // defeats DCE; never taken in practice
    }
}

// ---------------------------------------------------------------------------
// K2/K3: fused-level SpMM + ReLU, bf16 features / fp32 accumulate.
// WITHVAL: per-edge float val (full normalization in val, like R7 level-1).
//          Epilogue (SCALED) also emits y1/y2 = dis1/dis2-scaled outputs,
//          using ip1/ip2 (already resident — no new dependency).
// !WITHVAL: gathers pre-scaled y features, plain adds; row-side dis applied
//          in epilogue (relu(d*S) == d*relu(S), d>=0). One fewer VMEM stream.
// ROWS rows/wave; L = C/8 feature-lanes (uint4 = 8 bf16) x W edge-ways,
// 4-edge int4 batches (VGPR ~32; TLP > per-wave ILP — R5/R6 evidence).
// Blocks [0,nb2) = A2 (heavy, out col off C); rest = A1 (off 0).
// ---------------------------------------------------------------------------
template <int C, int ROWS, bool WITHVAL, bool SCALED>
__global__ __launch_bounds__(256) void spmm_level(
        const int* __restrict__ ip1, const int* __restrict__ col1,
        const float* __restrict__ val1,
        const int* __restrict__ ip2, const int* __restrict__ col2,
        const float* __restrict__ val2,
        const ushort* __restrict__ xin1, const ushort* __restrict__ xin2,
        ushort* __restrict__ rout,
        ushort* __restrict__ yout1, ushort* __restrict__ yout2,
        int n, int nb2) {
    constexpr int L    = C / 8;        // feature lanes per row
    constexpr int SUBL = 64 / ROWS;    // lanes per row
    constexpr int W    = SUBL / L;     // edge ways per row
    const int lane = threadIdx.x & 63;
    const int wave = threadIdx.x >> 6;
    const int sub  = lane / SUBL;
    const int li   = lane % SUBL;
    const int fl   = li % L;
    const int way  = li / L;

    int bid = blockIdx.x;
    const int* ip; const int* col; const float* val; const ushort* yin; int off;
    if (bid < nb2) {             ip = ip2; col = col2; val = val2; yin = xin2; off = C; }
    else           { bid -= nb2; ip = ip1; col = col1; val = val1; yin = xin1; off = 0; }

    const int row = (bid * 4 + wave) * ROWS + sub;
    if (row >= n) return;

    const ushort* xbase = yin + fl * 8;
    float acc[8];
#pragma unroll
    for (int j = 0; j < 8; ++j) acc[j] = 0.f;

    auto gat = [&](int c) -> uint4 {
        return *(const uint4*)(xbase + (size_t)c * C);
    };
    auto fmadd = [&](const uint4& u, float v) {
        acc[0] += v * bf_lo(u.x); acc[1] += v * bf_hi(u.x);
        acc[2] += v * bf_lo(u.y); acc[3] += v * bf_hi(u.y);
        acc[4] += v * bf_lo(u.z); acc[5] += v * bf_hi(u.z);
        acc[6] += v * bf_lo(u.w); acc[7] += v * bf_hi(u.w);
    };
    auto aadd = [&](const uint4& u) {
        acc[0] += bf_lo(u.x); acc[1] += bf_hi(u.x);
        acc[2] += bf_lo(u.y); acc[3] += bf_hi(u.y);
        acc[4] += bf_lo(u.z); acc[5] += bf_hi(u.z);
        acc[6] += bf_lo(u.w); acc[7] += bf_hi(u.w);
    };

    const int s = ip[row];
    const int e = ip[row + 1];
    int sv = (s + 3) & ~3; if (sv > e) sv = e;     // 16B-align vector loads
    const int nv = (e - sv) / (4 * W);

    // unaligned head (<=3 edges)
    for (int idx = s + way; idx < sv; idx += W) {
        if (WITHVAL) fmadd(gat(col[idx]), val[idx]); else aadd(gat(col[idx]));
    }
    // vector body: 4 edges per way per iteration
    const int*   cb = col + sv;
    const float* vb = val + sv;
    for (int i = 0; i < nv; ++i) {
        const int base = (i * W + way) * 4;
        const int4 cc = *(const int4*)(cb + base);
        if (WITHVAL) {
            const float4 vv = *(const float4*)(vb + base);
            const uint4 g0 = gat(cc.x), g1 = gat(cc.y), g2 = gat(cc.z), g3 = gat(cc.w);
            fmadd(g0, vv.x); fmadd(g1, vv.y); fmadd(g2, vv.z); fmadd(g3, vv.w);
        } else {
            const uint4 g0 = gat(cc.x), g1 = gat(cc.y), g2 = gat(cc.z), g3 = gat(cc.w);
            aadd(g0); aadd(g1); aadd(g2); aadd(g3);
        }
    }
    // scalar tail
    for (int idx = sv + nv * 4 * W + way; idx < e; idx += W) {
        if (WITHVAL) fmadd(gat(col[idx]), val[idx]); else aadd(gat(col[idx]));
    }

    // cross-way in-register reduction (stays within each row's subgroup)
#pragma unroll
    for (int m = L; m < SUBL; m <<= 1)
#pragma unroll
        for (int j = 0; j < 8; ++j) acc[j] += __shfl_xor(acc[j], m, 64);

    if (way == 0) {
        float r[8];
        if (WITHVAL) {
#pragma unroll
            for (int j = 0; j < 8; ++j) r[j] = fmaxf(acc[j], 0.f);
        } else {
            const float dsown = inv_sqrt_deg(e - s);   // row-side normalization
#pragma unroll
            for (int j = 0; j < 8; ++j) r[j] = fmaxf(dsown * acc[j], 0.f);
        }

        const size_t oidx = (size_t)row * (2 * C) + off + fl * 8;
        uint4 p;
        p.x = f2bf(r[0]) | (f2bf(r[1]) << 16);
        p.y = f2bf(r[2]) | (f2bf(r[3]) << 16);
        p.z = f2bf(r[4]) | (f2bf(r[5]) << 16);
        p.w = f2bf(r[6]) | (f2bf(r[7]) << 16);
        *(uint4*)(rout + oidx) = p;

        if (SCALED) {
            const float s1 = inv_sqrt_deg(ip1[row + 1] - ip1[row]);
            const float s2 = inv_sqrt_deg(ip2[row + 1] - ip2[row]);
            uint4 q1, q2;
            q1.x = f2bf(s1*r[0]) | (f2bf(s1*r[1]) << 16);
            q1.y = f2bf(s1*r[2]) | (f2bf(s1*r[3]) << 16);
            q1.z = f2bf(s1*r[4]) | (f2bf(s1*r[5]) << 16);
            q1.w = f2bf(s1*r[6]) | (f2bf(s1*r[7]) << 16);
            q2.x = f2bf(s2*r[0]) | (f2bf(s2*r[1]) << 16);
            q2.y = f2bf(s2*r[2]) | (f2bf(s2*r[3]) << 16);
            q2.z = f2bf(s2*r[4]) | (f2bf(s2*r[5]) << 16);
            q2.w = f2bf(s2*r[6]) | (f2bf(s2*r[7]) << 16);
            *(uint4*)(yout1 + oidx) = q1;
            *(uint4*)(yout2 + oidx) = q2;
        }
    }
}

// ---------------------------------------------------------------------------
// K4: out = [r0 | r1 | r2] @ w_classify  (bf16 features, fp32 weights in LDS)
// ---------------------------------------------------------------------------
#define CDIM 224
#define OUT_C 16
__global__ void classify_kernel(const ushort* __restrict__ r0,
                                const ushort* __restrict__ r1,
                                const ushort* __restrict__ r2,
                                const float* __restrict__ w,
                                float* __restrict__ out, int n) {
    __shared__ float wl[CDIM * OUT_C];
    const int tid = threadIdx.x;
    for (int i = tid; i < CDIM * OUT_C; i += blockDim.x) wl[i] = w[i];
    __syncthreads();
    const int row = blockIdx.x * 16 + tid / 16;
    const int o   = tid % 16;
    if (row >= n) return;
    float acc = 0.f;

    const uint4* a = (const uint4*)(r0 + (size_t)row * 32);
#pragma unroll
    for (int q = 0; q < 4; ++q) {
        uint4 u = a[q]; int j = q * 8;
        acc += bf_lo(u.x) * wl[(j+0)*OUT_C + o];  acc += bf_hi(u.x) * wl[(j+1)*OUT_C + o];
        acc += bf_lo(u.y) * wl[(j+2)*OUT_C + o];  acc += bf_hi(u.y) * wl[(j+3)*OUT_C + o];
        acc += bf_lo(u.z) * wl[(j+4)*OUT_C + o];  acc += bf_hi(u.z) * wl[(j+5)*OUT_C + o];
        acc += bf_lo(u.w) * wl[(j+6)*OUT_C + o];  acc += bf_hi(u.w) * wl[(j+7)*OUT_C + o];
    }
    const uint4* b = (const uint4*)(r1 + (size_t)row * 64);
#pragma unroll
    for (int q = 0; q < 8; ++q) {
        uint4 u = b[q]; int j = 32 + q * 8;
        acc += bf_lo(u.x) * wl[(j+0)*OUT_C + o];  acc += bf_hi(u.x) * wl[(j+1)*OUT_C + o];
        acc += bf_lo(u.y) * wl[(j+2)*OUT_C + o];  acc += bf_hi(u.y) * wl[(j+3)*OUT_C + o];
        acc += bf_lo(u.z) * wl[(j+4)*OUT_C + o];  acc += bf_hi(u.z) * wl[(j+5)*OUT_C + o];
        acc += bf_lo(u.w) * wl[(j+6)*OUT_C + o];  acc += bf_hi(u.w) * wl[(j+7)*OUT_C + o];
    }
    const uint4* c = (const uint4*)(r2 + (size_t)row * 128);
#pragma unroll
    for (int q = 0; q < 16; ++q) {
        uint4 u = c[q]; int j = 96 + q * 8;
        acc += bf_lo(u.x) * wl[(j+0)*OUT_C + o];  acc += bf_hi(u.x) * wl[(j+1)*OUT_C + o];
        acc += bf_lo(u.y) * wl[(j+2)*OUT_C + o];  acc += bf_hi(u.y) * wl[(j+3)*OUT_C + o];
        acc += bf_lo(u.z) * wl[(j+4)*OUT_C + o];  acc += bf_hi(u.z) * wl[(j+5)*OUT_C + o];
        acc += bf_lo(u.w) * wl[(j+6)*OUT_C + o];  acc += bf_hi(u.w) * wl[(j+7)*OUT_C + o];
    }
    out[(size_t)row * OUT_C + o] = acc;
}

// ---------------------------------------------------------------------------
extern "C" void kernel_launch(void* const* d_in, const int* in_sizes, int n_in,
                              void* d_out, int out_size, void* d_ws, size_t ws_size,
                              hipStream_t stream) {
    const float* x   = (const float*)d_in[0];
    const float* we  = (const float*)d_in[1];
    const float* wc  = (const float*)d_in[2];
    const int*   a1r = (const int*)  d_in[3];
    const int*   a1c = (const int*)  d_in[4];
    const float* a1v = (const float*)d_in[5];
    const int*   a2r = (const int*)  d_in[6];
    const int*   a2c = (const int*)  d_in[7];
    const float* a2v = (const float*)d_in[8];
    float* out = (float*)d_out;

    const int E1 = in_sizes[3];
    const int E2 = in_sizes[6];
    const int n  = in_sizes[0] / IN_C;   // 20000

    // Workspace (bf16): r0[n*32] r1[n*64] r2[n*128] y1_1[n*64] y2_1[n*64],
    // then ip1/ip2/dummy (int)
    ushort* r0   = (ushort*)d_ws;
    ushort* r1   = r0   + (size_t)n * 32;
    ushort* r2   = r1   + (size_t)n * 64;
    ushort* y1_1 = r2   + (size_t)n * 128;
    ushort* y2_1 = y1_1 + (size_t)n * 64;
    int*    ip1  = (int*)(y2_1 + (size_t)n * 64);
    int*    ip2  = ip1 + (n + 1);
    float*  dummy = (float*)(ip2 + (n + 1));

    // K1: fused prep (R7 structure: embed + indptrs + warm-touch)
    {
        const int nbE = (n + 15) / 16;
        const int nbI = (n + 1 + 255) / 256;
        const int nbT = 512;
        prep_kernel<<<nbE + nbI + nbT, 256, 0, stream>>>(
            x, we, r0, a1r, E1, ip1, a2r, E2, ip2, a2c, a2v, dummy,
            n, nbE, nbI, nbT);
    }
    // K2: level 1 (C=32, ROWS=2, with val) + scaled outputs for level 2
    {
        const int nb = (n + 7) / 8;
        spmm_level<32, 2, true, true><<<2 * nb, 256, 0, stream>>>(
            ip1, a1c, a1v, ip2, a2c, a2v, r0, r0, r1, y1_1, y2_1, n, nb);
    }
    // K3: level 2 (C=64, ROWS=1, val-free: gathers pre-scaled y)
    {
        const int nb = (n + 3) / 4;
        spmm_level<64, 1, false, false><<<2 * nb, 256, 0, stream>>>(
            ip1, a1c, nullptr, ip2, a2c, nullptr, y1_1, y2_1, r2,
            nullptr, nullptr, n, nb);
    }
    // K4: fused concat + classify
    classify_kernel<<<(n + 15) / 16, 256, 0, stream>>>(r0, r1, r2, wc, out, n);
}